// Round 3
// baseline (519.308 us; speedup 1.0000x reference)
//
#include <hip/hip_runtime.h>

#define N_NODES 50000
#define L_LAYERS 2
#define F_IN 128
#define F_OUT 32
#define E_L 800000
#define NEG_SLOPE 0.2f
#define LN 100000                 // L_LAYERS * N_NODES
#define NE (2 * E_L)              // 1,600,000 random edges
#define BSH 7                     // 128 nodes per bucket
#define BNODES 128
#define NB ((N_NODES + BNODES - 1) / BNODES)   // 391
#define CAP 4544                  // mean 4096 + 7 sigma (64)
#define PCHUNK 4000
#define PBLOCKS 400               // PBLOCKS * PCHUNK == NE exactly

// ---------------------------------------------------------------------------
// K1: bucket partition. Edge (src,trg,l) -> trg-bucket entry packed
// (n_low:7 | l:1 | u:17), and src-bucket 1-byte entry (s_low:7 | l:1) for
// degree counting. Block-level LDS histograms reserve contiguous per-bucket
// ranges (few global atomics, clustered writes -> no line amplification).
// ---------------------------------------------------------------------------
__global__ __launch_bounds__(256) void partition_kernel(
    const int* __restrict__ e0, const int* __restrict__ e1,
    int* __restrict__ cur_t, int* __restrict__ cur_s,
    int* __restrict__ trgbuf, unsigned char* __restrict__ srcbuf) {
    __shared__ int hist_t[NB], hist_s[NB], res_t[NB], res_s[NB];
    const int t = threadIdx.x, b = blockIdx.x;
    for (int i = t; i < NB; i += 256) { hist_t[i] = 0; hist_s[i] = 0; }
    __syncthreads();
    const int base = b * PCHUNK;
    // phase A: count this block's edges per bucket
    for (int i = base + t; i < base + PCHUNK; i += 256) {
        const int l = (i >= E_L) ? 1 : 0;
        const int e = i - l * E_L;
        const int* ei = l ? e1 : e0;
        const int src = ei[e], trg = ei[E_L + e];
        atomicAdd(&hist_t[trg >> BSH], 1);
        atomicAdd(&hist_s[src >> BSH], 1);
    }
    __syncthreads();
    // phase B: reserve global ranges per bucket
    for (int i = t; i < NB; i += 256) {
        res_t[i] = hist_t[i] ? atomicAdd(&cur_t[i], hist_t[i]) : 0;
        res_s[i] = hist_s[i] ? atomicAdd(&cur_s[i], hist_s[i]) : 0;
    }
    __syncthreads();
    for (int i = t; i < NB; i += 256) { hist_t[i] = 0; hist_s[i] = 0; }
    __syncthreads();
    // phase C: write entries (edges re-read from L2-hot lines)
    for (int i = base + t; i < base + PCHUNK; i += 256) {
        const int l = (i >= E_L) ? 1 : 0;
        const int e = i - l * E_L;
        const int* ei = l ? e1 : e0;
        const int src = ei[e], trg = ei[E_L + e];
        const int tb = trg >> BSH, sb = src >> BSH;
        const int st = res_t[tb] + atomicAdd(&hist_t[tb], 1);
        const int ss = res_s[sb] + atomicAdd(&hist_s[sb], 1);
        if (st < CAP)
            trgbuf[tb * CAP + st] =
                ((trg & (BNODES - 1)) << 18) | (l << 17) | (src + l * N_NODES);
        if (ss < CAP)
            srcbuf[sb * CAP + ss] =
                (unsigned char)((src & (BNODES - 1)) | (l << 7));
    }
}

// ---------------------------------------------------------------------------
// K2: per-bucket LDS histograms -> dense cnt_trg / cnt_src (replaces the
// 3.2M-global-atomic deg kernel and the whole scan).
// ---------------------------------------------------------------------------
__global__ __launch_bounds__(256) void count_kernel(
    const int* __restrict__ cur_t, const int* __restrict__ cur_s,
    const int* __restrict__ trgbuf, const unsigned char* __restrict__ srcbuf,
    int* __restrict__ cnt_trg, int* __restrict__ cnt_src) {
    __shared__ int ht[256], hs[256];
    const int t = threadIdx.x, b = blockIdx.x;
    ht[t] = 0; hs[t] = 0;
    __syncthreads();
    const int ct = min(cur_t[b], CAP), cs = min(cur_s[b], CAP);
    for (int i = t; i < ct; i += 256) {
        const int p = trgbuf[b * CAP + i];
        atomicAdd(&ht[((p >> 17) & 1) * 128 + ((p >> 18) & 127)], 1);
    }
    for (int i = t; i < cs; i += 256) {
        const unsigned char c = srcbuf[b * CAP + i];
        atomicAdd(&hs[(c >> 7) * 128 + (c & 127)], 1);
    }
    __syncthreads();
    const int n = b * BNODES + (t & 127);
    if (n < N_NODES) {
        const int v = (t >> 7) * N_NODES + n;  // hist idx == t
        cnt_trg[v] = ht[t];
        cnt_src[v] = hs[t];
    }
}

// ---------------------------------------------------------------------------
// K3: proj = (x @ W_proj^T) * outdeg_inv, scaled[(l*N+n)*32+f].
// ---------------------------------------------------------------------------
__global__ __launch_bounds__(256) void proj_kernel(
    const float* __restrict__ x, const float* __restrict__ Wp,
    const int* __restrict__ cnt_trg, float* __restrict__ scaled) {
    __shared__ float Wtt[64][132];   // Wtt[o][k] = Wp[o*128+k], pad -> no conflict
    __shared__ float xt[8][F_IN];
    const int t = threadIdx.x;
    for (int i = t; i < 64 * F_IN; i += 256) {
        int o = i >> 7, k = i & 127;
        Wtt[o][k] = Wp[i];
    }
    const int lane = t & 63, w = t >> 6;
    const int ntiles = N_NODES / 8;          // 6250, exact
    for (int tile = blockIdx.x; tile < ntiles; tile += gridDim.x) {
        const int base = tile * 8;
        __syncthreads();                     // also covers initial W-load
        ((float4*)&xt[0][0])[t] = ((const float4*)(x + (size_t)base * F_IN))[t];
        __syncthreads();
        const int n0 = w, n1 = w + 4;
        float acc0 = 0.f, acc1 = 0.f;
        #pragma unroll
        for (int k = 0; k < F_IN; k += 4) {
            float4 wv = *(const float4*)&Wtt[lane][k];
            float4 x0 = *(const float4*)&xt[n0][k];
            float4 x1 = *(const float4*)&xt[n1][k];
            acc0 += wv.x * x0.x + wv.y * x0.y + wv.z * x0.z + wv.w * x0.w;
            acc1 += wv.x * x1.x + wv.y * x1.y + wv.z * x1.z + wv.w * x1.w;
        }
        const int l = lane >> 5, f = lane & 31;
        {
            const int v = l * N_NODES + base + n0;
            const float od = 1.0f / sqrtf((float)(cnt_trg[v] + 2));
            scaled[(size_t)v * F_OUT + f] = acc0 * od;
        }
        {
            const int v = l * N_NODES + base + n1;
            const float od = 1.0f / sqrtf((float)(cnt_trg[v] + 2));
            scaled[(size_t)v * F_OUT + f] = acc1 * od;
        }
    }
}

// ---------------------------------------------------------------------------
// K4: fused per-bucket aggregate (LDS float atomics) + self/inter fold +
// leaky + merge GEMM (64->32) -> out. One block per bucket, 512 threads.
// 16 lanes/edge, float2 chunks: LDS bank pattern is 4-way (cheap, m136).
// ---------------------------------------------------------------------------
__global__ __launch_bounds__(512) void mega_kernel(
    const int* __restrict__ cur_t, const int* __restrict__ trgbuf,
    const float* __restrict__ scaled, const int* __restrict__ cnt_src,
    const float* __restrict__ Wm, const float* __restrict__ bias,
    float* __restrict__ out) {
    __shared__ float agg[BNODES][64];   // 32 KB, agg[n_low][l*32+f]
    __shared__ float Wt[64][32];        // 8 KB, Wt[k][o] = Wm[o*64+k]
    __shared__ float bs[64];
    const int t = threadIdx.x, b = blockIdx.x;
    for (int i = t; i < 64 * 32; i += 512) Wt[i >> 5][i & 31] = Wm[(i & 31) * 64 + (i >> 5)];
    if (t < 64) bs[t] = bias[t];
    for (int i = t; i < BNODES * 64 / 4; i += 512)
        ((float4*)&agg[0][0])[i] = make_float4(0.f, 0.f, 0.f, 0.f);
    __syncthreads();
    const int cnt = min(cur_t[b], CAP);
    const int li = t & 15;              // lane within 16-lane edge group
    const int grp = t >> 4;             // 32 edges per block pass
    const int f2 = li * 2;
    for (int e = grp; e < cnt; e += 32) {
        const int p = trgbuf[b * CAP + e];
        const int u = p & 0x1FFFF;
        const int lq = (p >> 17) & 1;
        const int r = (p >> 18) & 127;
        const float2 gv = *(const float2*)(scaled + (size_t)u * F_OUT + f2);
        atomicAdd(&agg[r][lq * 32 + f2],     gv.x);
        atomicAdd(&agg[r][lq * 32 + f2 + 1], gv.y);
    }
    __syncthreads();
    // fold: (rand_agg + self + inter) * indeg_inv + bias -> leaky, in place
    for (int i = t; i < BNODES * 64; i += 512) {
        const int r = i >> 6, k = i & 63;
        const int n = b * BNODES + r;
        if (n < N_NODES) {
            const int l = k >> 5, f = k & 31;
            const float add = scaled[(size_t)n * F_OUT + f]
                            + scaled[(size_t)(N_NODES + n) * F_OUT + f];
            const float id = 1.0f / sqrtf((float)(cnt_src[l * N_NODES + n] + 2));
            const float tot = (agg[r][k] + add) * id + bs[k];
            agg[r][k] = (tot >= 0.f) ? tot : NEG_SLOPE * tot;
        }
    }
    __syncthreads();
    // merge GEMM: out[n][o] = sum_k h[n][k] * Wm[o][k]
    const int o = t & 31;
    for (int r = t >> 5; r < BNODES; r += 16) {
        const int n = b * BNODES + r;
        if (n >= N_NODES) break;
        float acc = 0.f;
        #pragma unroll
        for (int k = 0; k < 64; ++k)
            acc += agg[r][k] * Wt[k][o];   // agg: broadcast; Wt: conflict-free
        out[(size_t)n * F_OUT + o] = acc;
    }
}

// ---------------------------------------------------------------------------
extern "C" void kernel_launch(void* const* d_in, const int* in_sizes, int n_in,
                              void* d_out, int out_size, void* d_ws, size_t ws_size,
                              hipStream_t stream) {
    const float* x    = (const float*)d_in[0];
    const int*   e0   = (const int*)d_in[1];
    const int*   e1   = (const int*)d_in[2];
    const float* Wp   = (const float*)d_in[3];
    const float* Wm   = (const float*)d_in[4];
    const float* bias = (const float*)d_in[5];
    float* out = (float*)d_out;

    // workspace (~20.7 MB):
    float* scaled = (float*)d_ws;                         // 12.8 MB
    // srcbuf aliases scaled: written by partition, read by count, dead
    // before proj overwrites the region.
    unsigned char* srcbuf = (unsigned char*)d_ws;         // NB*CAP = 1.78 MB
    int* trgbuf  = (int*)((char*)d_ws + (size_t)LN * F_OUT * sizeof(float));
    int* cur_t   = trgbuf + (size_t)NB * CAP;             // NB ints
    int* cur_s   = cur_t + NB;                            // NB ints
    int* cnt_trg = cur_s + NB;                            // 400 KB
    int* cnt_src = cnt_trg + LN;                          // 400 KB

    hipMemsetAsync(cur_t, 0, 2 * NB * sizeof(int), stream);

    partition_kernel<<<PBLOCKS, 256, 0, stream>>>(e0, e1, cur_t, cur_s,
                                                  trgbuf, srcbuf);
    count_kernel<<<NB, 256, 0, stream>>>(cur_t, cur_s, trgbuf, srcbuf,
                                         cnt_trg, cnt_src);
    proj_kernel<<<1024, 256, 0, stream>>>(x, Wp, cnt_trg, scaled);
    mega_kernel<<<NB, 512, 0, stream>>>(cur_t, trgbuf, scaled, cnt_src,
                                        Wm, bias, out);
}

// Round 5
// 189.184 us; speedup vs baseline: 2.7450x; 2.7450x over previous
//
#include <hip/hip_runtime.h>

#define N_NODES 50000
#define F_IN 128
#define F_OUT 32
#define E_L 800000
#define NEG_SLOPE 0.2f
#define LN 100000                 // 2 * N_NODES
#define NE 1600000                // 2 * E_L random edges
#define BSH 6                     // 64 nodes per bucket
#define BNODES 64
#define NB 782                    // ceil(50000/64)
#define CAP 2368                  // mean 2046 + ~7 sigma, mult of 64
#define PBLOCKS 256
#define PCHUNK 6250               // PBLOCKS * PCHUNK == NE exactly

// ---------------------------------------------------------------------------
// K1: bucket partition. trg-bucket entry packed (rr:7 | u:17) where
// rr = (l<<6)|(trg&63), u = src + l*N. src-bucket 1-byte entry (l<<6)|(src&63)
// for degree counting. Block-level LDS hist reserves contiguous ranges ->
// few global atomics, clustered writes (no 64B-line write amplification).
// ---------------------------------------------------------------------------
__global__ __launch_bounds__(512) void partition_kernel(
    const int* __restrict__ e0, const int* __restrict__ e1,
    int* __restrict__ cur_t, int* __restrict__ cur_s,
    int* __restrict__ trgbuf, unsigned char* __restrict__ srcbuf) {
    __shared__ int hist_t[NB], hist_s[NB], res_t[NB], res_s[NB];
    const int t = threadIdx.x, b = blockIdx.x;
    for (int i = t; i < NB; i += 512) { hist_t[i] = 0; hist_s[i] = 0; }
    __syncthreads();
    const int base = b * PCHUNK;
    for (int i = base + t; i < base + PCHUNK; i += 512) {
        const int l = (i >= E_L) ? 1 : 0;
        const int e = i - l * E_L;
        const int* ei = l ? e1 : e0;
        const int src = ei[e], trg = ei[E_L + e];
        atomicAdd(&hist_t[trg >> BSH], 1);
        atomicAdd(&hist_s[src >> BSH], 1);
    }
    __syncthreads();
    for (int i = t; i < NB; i += 512) {
        res_t[i] = hist_t[i] ? atomicAdd(&cur_t[i], hist_t[i]) : 0;
        res_s[i] = hist_s[i] ? atomicAdd(&cur_s[i], hist_s[i]) : 0;
    }
    __syncthreads();
    for (int i = t; i < NB; i += 512) { hist_t[i] = 0; hist_s[i] = 0; }
    __syncthreads();
    for (int i = base + t; i < base + PCHUNK; i += 512) {
        const int l = (i >= E_L) ? 1 : 0;
        const int e = i - l * E_L;
        const int* ei = l ? e1 : e0;
        const int src = ei[e], trg = ei[E_L + e];
        const int tb = trg >> BSH, sb = src >> BSH;
        const int st = res_t[tb] + atomicAdd(&hist_t[tb], 1);
        const int ss = res_s[sb] + atomicAdd(&hist_s[sb], 1);
        if (st < CAP)
            trgbuf[tb * CAP + st] =
                (((l << 6) | (trg & 63)) << 17) | (src + l * N_NODES);
        if (ss < CAP)
            srcbuf[sb * CAP + ss] = (unsigned char)((l << 6) | (src & 63));
    }
}

// ---------------------------------------------------------------------------
// K2: per-bucket LDS hists -> dense cnt_trg / cnt_src (128 rows per bucket).
// ---------------------------------------------------------------------------
__global__ __launch_bounds__(256) void count_kernel(
    const int* __restrict__ cur_t, const int* __restrict__ cur_s,
    const int* __restrict__ trgbuf, const unsigned char* __restrict__ srcbuf,
    int* __restrict__ cnt_trg, int* __restrict__ cnt_src) {
    __shared__ int ht[128], hs[128];
    const int t = threadIdx.x, b = blockIdx.x;
    if (t < 128) { ht[t] = 0; hs[t] = 0; }
    __syncthreads();
    const int ct = min(cur_t[b], CAP), cs = min(cur_s[b], CAP);
    for (int i = t; i < ct; i += 256)
        atomicAdd(&ht[(trgbuf[b * CAP + i] >> 17) & 127], 1);
    for (int i = t; i < cs; i += 256)
        atomicAdd(&hs[srcbuf[b * CAP + i] & 127], 1);
    __syncthreads();
    if (t < 128) {
        const int l = t >> 6, n = b * BNODES + (t & 63);
        if (n < N_NODES) {
            cnt_trg[l * N_NODES + n] = ht[t];
            cnt_src[l * N_NODES + n] = hs[t];
        }
    }
}

// ---------------------------------------------------------------------------
// K3: proj = (x @ W_proj^T) * outdeg_inv, scaled[(l*N+n)*32+f]. (unchanged)
// ---------------------------------------------------------------------------
__global__ __launch_bounds__(256) void proj_kernel(
    const float* __restrict__ x, const float* __restrict__ Wp,
    const int* __restrict__ cnt_trg, float* __restrict__ scaled) {
    __shared__ float Wtt[64][132];   // Wtt[o][k] = Wp[o*128+k]
    __shared__ float xt[8][F_IN];
    const int t = threadIdx.x;
    for (int i = t; i < 64 * F_IN; i += 256) {
        int o = i >> 7, k = i & 127;
        Wtt[o][k] = Wp[i];
    }
    const int lane = t & 63, w = t >> 6;
    const int ntiles = N_NODES / 8;          // 6250, exact
    for (int tile = blockIdx.x; tile < ntiles; tile += gridDim.x) {
        const int base = tile * 8;
        __syncthreads();
        ((float4*)&xt[0][0])[t] = ((const float4*)(x + (size_t)base * F_IN))[t];
        __syncthreads();
        const int n0 = w, n1 = w + 4;
        float acc0 = 0.f, acc1 = 0.f;
        #pragma unroll
        for (int k = 0; k < F_IN; k += 4) {
            float4 wv = *(const float4*)&Wtt[lane][k];
            float4 x0 = *(const float4*)&xt[n0][k];
            float4 x1 = *(const float4*)&xt[n1][k];
            acc0 += wv.x * x0.x + wv.y * x0.y + wv.z * x0.z + wv.w * x0.w;
            acc1 += wv.x * x1.x + wv.y * x1.y + wv.z * x1.z + wv.w * x1.w;
        }
        const int l = lane >> 5, f = lane & 31;
        {
            const int v = l * N_NODES + base + n0;
            const float od = 1.0f / sqrtf((float)(cnt_trg[v] + 2));
            scaled[(size_t)v * F_OUT + f] = acc0 * od;
        }
        {
            const int v = l * N_NODES + base + n1;
            const float od = 1.0f / sqrtf((float)(cnt_trg[v] + 2));
            scaled[(size_t)v * F_OUT + f] = acc1 * od;
        }
    }
}

// ---------------------------------------------------------------------------
// K4: per-bucket LDS counting-sort -> node-parallel register gather (no float
// atomics) -> fold self/inter + 1/sqrt(deg) + bias + leaky -> 64->32 GEMM.
// 782 blocks x 512 threads, ~36KB LDS -> 4 blocks/CU.
// ---------------------------------------------------------------------------
__global__ __launch_bounds__(512) void mega_kernel(
    const int* __restrict__ cur_t, const int* __restrict__ trgbuf,
    const int* __restrict__ cnt_trg, const int* __restrict__ cnt_src,
    const float* __restrict__ scaled, const float* __restrict__ Wm,
    const float* __restrict__ bias, float* __restrict__ out) {
    __shared__ int   colx[CAP];        // 9.25 KB sorted sources
    __shared__ int   rp[128], rdeg[128], cursor[128], sc[128];
    __shared__ float h[BNODES][64];    // 16 KB
    __shared__ float Wt[64][32];       // 8 KB, Wt[k][o] = Wm[o*64+k]
    __shared__ float bs[64];
    const int t = threadIdx.x, b = blockIdx.x;
    for (int i = t; i < 2048; i += 512) Wt[i >> 5][i & 31] = Wm[(i & 31) * 64 + (i >> 5)];
    if (t < 64) bs[t] = bias[t];
    // row degrees -> exclusive scan -> segment starts
    int cnt_r = 0;
    if (t < 128) {
        const int l = t >> 6, n = b * BNODES + (t & 63);
        cnt_r = (n < N_NODES) ? cnt_trg[l * N_NODES + n] : 0;
        rdeg[t] = cnt_r; sc[t] = cnt_r;
    }
    __syncthreads();
    for (int off = 1; off < 128; off <<= 1) {
        int add = (t < 128 && t >= off) ? sc[t - off] : 0;
        __syncthreads();
        if (t < 128) sc[t] += add;
        __syncthreads();
    }
    if (t < 128) { rp[t] = sc[t] - cnt_r; cursor[t] = sc[t] - cnt_r; }
    __syncthreads();
    // counting-sort scatter (LDS int atomics + LDS writes only)
    const int total = min(cur_t[b], CAP);
    for (int i = t; i < total; i += 512) {
        const int p = trgbuf[b * CAP + i];
        const int slot = atomicAdd(&cursor[(p >> 17) & 127], 1);
        colx[slot] = p & 0x1FFFF;
    }
    __syncthreads();
    // node-parallel gather: 8 lanes x float4 per (node,layer) row
    const int grp = t >> 3, f = (t & 7) * 4;
    #pragma unroll
    for (int rr0 = 0; rr0 < 2; ++rr0) {
        const int rr = grp + rr0 * 64;
        const int l = rr >> 6, nl = rr & 63, n = b * BNODES + nl;
        if (n < N_NODES) {
            const int s0 = rp[rr], d = rdeg[rr];
            float4 acc = make_float4(0.f, 0.f, 0.f, 0.f);
            #pragma unroll 4
            for (int i = 0; i < d; ++i) {
                const int u = colx[s0 + i];          // 8-lane broadcast
                const float4 g = *(const float4*)(scaled + (size_t)u * F_OUT + f);
                acc.x += g.x; acc.y += g.y; acc.z += g.z; acc.w += g.w;
            }
            const int v = l * N_NODES + n, vp = (1 - l) * N_NODES + n;
            const float4 sv = *(const float4*)(scaled + (size_t)v  * F_OUT + f);
            const float4 pv = *(const float4*)(scaled + (size_t)vp * F_OUT + f);
            const float id = rsqrtf((float)(cnt_src[v] + 2));
            float4 hv;
            hv.x = (acc.x + sv.x + pv.x) * id + bs[l * 32 + f + 0];
            hv.y = (acc.y + sv.y + pv.y) * id + bs[l * 32 + f + 1];
            hv.z = (acc.z + sv.z + pv.z) * id + bs[l * 32 + f + 2];
            hv.w = (acc.w + sv.w + pv.w) * id + bs[l * 32 + f + 3];
            hv.x = (hv.x >= 0.f) ? hv.x : NEG_SLOPE * hv.x;
            hv.y = (hv.y >= 0.f) ? hv.y : NEG_SLOPE * hv.y;
            hv.z = (hv.z >= 0.f) ? hv.z : NEG_SLOPE * hv.z;
            hv.w = (hv.w >= 0.f) ? hv.w : NEG_SLOPE * hv.w;
            *(float4*)&h[nl][l * 32 + f] = hv;       // full-row b128, uniform banks
        }
    }
    __syncthreads();
    // merge GEMM: out[n][o] = sum_k h[n][k] * Wm[o][k]
    for (int i = t; i < BNODES * 32; i += 512) {
        const int nl = i >> 5, o = i & 31, n = b * BNODES + nl;
        if (n < N_NODES) {
            float acc = 0.f;
            #pragma unroll
            for (int k = 0; k < 64; ++k)
                acc += h[nl][k] * Wt[k][o];          // h: broadcast; Wt: cf
            out[(size_t)n * F_OUT + o] = acc;
        }
    }
}

// ---------------------------------------------------------------------------
extern "C" void kernel_launch(void* const* d_in, const int* in_sizes, int n_in,
                              void* d_out, int out_size, void* d_ws, size_t ws_size,
                              hipStream_t stream) {
    const float* x    = (const float*)d_in[0];
    const int*   e0   = (const int*)d_in[1];
    const int*   e1   = (const int*)d_in[2];
    const float* Wp   = (const float*)d_in[3];
    const float* Wm   = (const float*)d_in[4];
    const float* bias = (const float*)d_in[5];
    float* out = (float*)d_out;

    // workspace (~21.0 MB)
    float* scaled = (float*)d_ws;                         // 12.8 MB
    unsigned char* srcbuf = (unsigned char*)d_ws;         // aliases scaled (1.85 MB),
                                                          // dead before proj writes
    int* trgbuf  = (int*)((char*)d_ws + (size_t)LN * F_OUT * sizeof(float)); // 7.4 MB
    int* cur_t   = trgbuf + (size_t)NB * CAP;
    int* cur_s   = cur_t + NB;
    int* cnt_trg = cur_s + NB;                            // 400 KB
    int* cnt_src = cnt_trg + LN;                          // 400 KB

    hipMemsetAsync(cur_t, 0, 2 * NB * sizeof(int), stream);

    partition_kernel<<<PBLOCKS, 512, 0, stream>>>(e0, e1, cur_t, cur_s,
                                                  trgbuf, srcbuf);
    count_kernel<<<NB, 256, 0, stream>>>(cur_t, cur_s, trgbuf, srcbuf,
                                         cnt_trg, cnt_src);
    proj_kernel<<<1024, 256, 0, stream>>>(x, Wp, cnt_trg, scaled);
    mega_kernel<<<NB, 512, 0, stream>>>(cur_t, trgbuf, cnt_trg, cnt_src,
                                        scaled, Wm, bias, out);
}